// Round 6
// baseline (25.790 us; speedup 1.0000x reference)
//
#include <hip/hip_runtime.h>

#define NB 4
#define NV 4096
#define NF 8192
#define NP 6
#define NE 2048

#define NBLK 768          // exactly 3 blocks/CU x 256 CU -> one execution round
#define BPB  (NBLK / NB)  // 192 vol slices per batch (8192/192 = 42.67 faces each)

// ---------------------------------------------------------------------------
// Fused kernel, 768 blocks. Every block:
//   * volume slice: ~43 faces of batch bid/192   -> ws[NBLK + bid]
//   * chamfer chunk: 128 points of pp = bid>>5, chunk = bid&31 -> ws[bid]
// Edges live in registers (32/lane x {ax,ay,c}); points are wave-uniform.
// Butterfly mins batched 8 points at a time (8 parallel 6-step chains).
// ---------------------------------------------------------------------------
__global__ __launch_bounds__(256, 3) void fused_kernel(
    const float* __restrict__ xs,
    const float* __restrict__ pm,
    const float* __restrict__ em,
    const int*   __restrict__ faces,
    float* __restrict__ ws)
{
    __shared__ float2 sxy[128];
    __shared__ float  redv[256];
    __shared__ float  redc[4];

    const int bid  = blockIdx.x;
    const int tid  = threadIdx.x;
    const int lane = tid & 63;
    const int w    = tid >> 6;

    // ---------------- volume slice (registers die before chamfer loop) -----
    {
        const int vb   = bid / BPB;                // batch
        const int j    = bid % BPB;
        const int fs   = (j * NF) / BPB;
        const int fcnt = (((j + 1) * NF) / BPB) - fs;   // 42 or 43
        float fvol = 0.0f;
        if (tid < fcnt) {
            const int* fp = faces + (size_t)(vb * NF + fs + tid) * 3;
            int i0 = fp[0], i1 = fp[1], i2 = fp[2];
            const float* p0 = xs + (size_t)(vb * NV + i0) * 3;
            const float* p1 = xs + (size_t)(vb * NV + i1) * 3;
            const float* p2 = xs + (size_t)(vb * NV + i2) * 3;
            float a0 = p0[0], a1 = p0[1], a2 = p0[2];
            float b0 = p1[0], b1 = p1[1], b2 = p1[2];
            float c0 = p2[0], c1 = p2[1], c2 = p2[2];
            float crx = a1 * b2 - a2 * b1;
            float cry = a2 * b0 - a0 * b2;
            float crz = a0 * b1 - a1 * b0;
            fvol = (crx * c0 + cry * c1 + crz * c2) * (1.0f / 6.0f);
        }
        redv[tid] = fvol;
    }

    // ---------------- chamfer setup ----------------------------------------
    const int chunk = bid & 31;
    const int pp    = bid >> 5;            // b*NP + p
    const int p     = pp % NP;
    const int b     = pp / NP;

    // Project this chunk's 128 points into LDS.
    if (tid < 128) {
        int v = chunk * 128 + tid;
        const float* x3 = xs + (size_t)(b * NV + v) * 3;
        float x = x3[0], y = x3[1], z = x3[2];
        const float* M = pm + p * 12;                  // uniform -> s_load
        float px = fmaf(M[0], x, fmaf(M[1], y, fmaf(M[2],  z, M[3])));
        float py = fmaf(M[4], x, fmaf(M[5], y, fmaf(M[6],  z, M[7])));
        float pz = fmaf(M[8], x, fmaf(M[9], y, fmaf(M[10], z, M[11])));
        float inv = 1.0f / pz;
        sxy[tid] = make_float2(px * inv, py * inv);
    }

    // Edge table into registers: lane holds 32 of the 2048 edges.
    const float4* em4 = (const float4*)em + (size_t)pp * (NE / 2);
    float ax[32], ay[32], cc[32];
#pragma unroll
    for (int k = 0; k < 16; ++k) {
        float4 e = em4[k * 64 + lane];
        ax[2 * k]     = -2.0f * e.x;
        ay[2 * k]     = -2.0f * e.y;
        cc[2 * k]     = fmaf(e.x, e.x, e.y * e.y);
        ax[2 * k + 1] = -2.0f * e.z;
        ay[2 * k + 1] = -2.0f * e.w;
        cc[2 * k + 1] = fmaf(e.z, e.z, e.w * e.w);
    }
    __syncthreads();

    // ---------------- chamfer inner loop: batches of 8 points --------------
    float wsum = 0.0f;
    for (int qb = 0; qb < 32; qb += 8) {
        float mm[8];
#pragma unroll
        for (int q = 0; q < 8; ++q) {
            float2 pt = sxy[w * 32 + qb + q];   // uniform LDS broadcast
            float X = pt.x, Y = pt.y;

            float t0 = fmaf(ay[0], Y, fmaf(ax[0], X, cc[0]));
            float t1 = fmaf(ay[1], Y, fmaf(ax[1], X, cc[1]));
            float m0 = fminf(t0, t1);
            t0 = fmaf(ay[2], Y, fmaf(ax[2], X, cc[2]));
            t1 = fmaf(ay[3], Y, fmaf(ax[3], X, cc[3]));
            float m1 = fminf(t0, t1);
            t0 = fmaf(ay[4], Y, fmaf(ax[4], X, cc[4]));
            t1 = fmaf(ay[5], Y, fmaf(ax[5], X, cc[5]));
            float m2 = fminf(t0, t1);
            t0 = fmaf(ay[6], Y, fmaf(ax[6], X, cc[6]));
            t1 = fmaf(ay[7], Y, fmaf(ax[7], X, cc[7]));
            float m3 = fminf(t0, t1);
#pragma unroll
            for (int k = 8; k < 32; k += 8) {
                t0 = fmaf(ay[k + 0], Y, fmaf(ax[k + 0], X, cc[k + 0]));
                t1 = fmaf(ay[k + 1], Y, fmaf(ax[k + 1], X, cc[k + 1]));
                m0 = fminf(fminf(m0, t0), t1);             // v_min3_f32
                t0 = fmaf(ay[k + 2], Y, fmaf(ax[k + 2], X, cc[k + 2]));
                t1 = fmaf(ay[k + 3], Y, fmaf(ax[k + 3], X, cc[k + 3]));
                m1 = fminf(fminf(m1, t0), t1);
                t0 = fmaf(ay[k + 4], Y, fmaf(ax[k + 4], X, cc[k + 4]));
                t1 = fmaf(ay[k + 5], Y, fmaf(ax[k + 5], X, cc[k + 5]));
                m2 = fminf(fminf(m2, t0), t1);
                t0 = fmaf(ay[k + 6], Y, fmaf(ax[k + 6], X, cc[k + 6]));
                t1 = fmaf(ay[k + 7], Y, fmaf(ax[k + 7], X, cc[k + 7]));
                m3 = fminf(fminf(m3, t0), t1);
            }
            mm[q] = fminf(fminf(m0, m1), fminf(m2, m3));
            wsum += fmaf(X, X, Y * Y);      // x^2 term, added outside the min
        }

        // 8 interleaved 64-lane butterflies (independent chains -> pipelined)
#pragma unroll
        for (int off = 1; off < 64; off <<= 1) {
#pragma unroll
            for (int q = 0; q < 8; ++q)
                mm[q] = fminf(mm[q], __shfl_xor(mm[q], off));
        }
        wsum += ((mm[0] + mm[1]) + (mm[2] + mm[3])) +
                ((mm[4] + mm[5]) + (mm[6] + mm[7]));
    }

    // ---------------- block reductions -------------------------------------
    if (lane == 0) redc[w] = wsum;          // all lanes hold identical wsum
    __syncthreads();
    for (int st = 128; st > 0; st >>= 1) {
        if (tid < st) redv[tid] += redv[tid + st];
        __syncthreads();
    }
    if (tid == 0) {
        ws[bid]        = (redc[0] + redc[1]) + (redc[2] + redc[3]);
        ws[NBLK + bid] = redv[0];
    }
}

// ---------------------------------------------------------------------------
// Finalize: 1 block, 256 threads; wave b handles batch b. Deterministic.
// ---------------------------------------------------------------------------
__global__ __launch_bounds__(256) void finalize_kernel(
    const float* __restrict__ ws,
    const float* __restrict__ tv,
    float* __restrict__ out)
{
    const int tid  = threadIdx.x;
    const int b    = tid >> 6;
    const int lane = tid & 63;

    const float* cp = ws + b * BPB + lane * 3;            // 192 chamfer partials
    const float* vp = ws + NBLK + b * BPB + lane * 3;     // 192 vol partials
    float cs = cp[0] + cp[1] + cp[2];
    float vs = vp[0] + vp[1] + vp[2];
#pragma unroll
    for (int off = 1; off < 64; off <<= 1) {
        cs += __shfl_xor(cs, off);
        vs += __shfl_xor(vs, off);
    }
    if (lane == 0) {
        out[b] = cs * (1.0f / (NP * NV));
        float d = fabsf(vs) - tv[b];
        out[4 + b] = d * d;
    }
}

// ---------------------------------------------------------------------------
extern "C" void kernel_launch(void* const* d_in, const int* in_sizes, int n_in,
                              void* d_out, int out_size, void* d_ws, size_t ws_size,
                              hipStream_t stream) {
    const float* xs    = (const float*)d_in[0];
    const float* pm    = (const float*)d_in[1];
    const float* em    = (const float*)d_in[2];
    const int*   faces = (const int*)d_in[3];
    const float* tv    = (const float*)d_in[4];
    float* out = (float*)d_out;
    float* ws  = (float*)d_ws;            // 1536 floats of partials

    fused_kernel<<<NBLK, 256, 0, stream>>>(xs, pm, em, faces, ws);
    finalize_kernel<<<1, 256, 0, stream>>>(ws, tv, out);
}